// Round 1
// baseline (1036.856 us; speedup 1.0000x reference)
//
#include <hip/hip_runtime.h>
#include <stdint.h>

#define BATCH 4096
#define PLEN  512
#define NSTEP 511
#define FD    64

// ws layout:
//   [0, 2048)                      : colmax bits (512 x u32), init 1.0f, atomicMax'ed
//   [2048, 2048 + BATCH*PLEN)      : idx bytes (u8 per (b,t)), t=511 slot written as 0
//   [2048 + BATCH*PLEN, +4MB)      : PT: transposed/packed connection, float4
//                                    PT4[k*1024 + r*64 + j] = {M_k[4r+c][j], c=0..3}
// total: 6,293,504 bytes

__global__ void k_init_colmax(unsigned int* cm) {
    int t = threadIdx.x;
    if (t < PLEN) cm[t] = 0x3f800000u; // bits of 1.0f
}

__global__ void k_colmax(const float* __restrict__ bp, unsigned int* __restrict__ cm) {
    __shared__ float red[256];
    int tx = threadIdx.x & 63;
    int ty = threadIdx.x >> 6;
    int t  = blockIdx.x * 64 + tx;            // 0..511
    int b0 = blockIdx.y * 256 + ty * 64;      // 64-row group per wave
    const float* p = bp + (size_t)b0 * PLEN + t;
    float m = 0.0f;
    #pragma unroll 4
    for (int r = 0; r < 64; ++r) {
        m = fmaxf(m, p[(size_t)r * PLEN]);
    }
    red[threadIdx.x] = m;
    __syncthreads();
    if (ty == 0) {
        m = fmaxf(fmaxf(red[tx], red[64 + tx]), fmaxf(red[128 + tx], red[192 + tx]));
        atomicMax((int*)&cm[t], __float_as_int(m)); // all values >= 0 -> int-bits monotone
    }
}

__global__ void k_idx(const float* __restrict__ bp, const unsigned int* __restrict__ cm,
                      uint8_t* __restrict__ idx) {
    int gid = blockIdx.x * blockDim.x + threadIdx.x; // over BATCH*PLEN
    int t = gid & (PLEN - 1);
    uint8_t k = 0;
    if (t < NSTEP) {
        float mx = __uint_as_float(cm[t]);    // = max(batch max, 1.0)
        float v  = bp[gid];
        float q  = (v * 256.0f) / mx;         // exact reference order: (bp*base_dim)/mx
        int ik = (int)q;                      // trunc toward zero, matches astype(int32)
        ik = ik < 0 ? 0 : (ik > 255 ? 255 : ik);
        k = (uint8_t)ik;
    }
    idx[gid] = k;
}

__global__ void k_transpose(const float* __restrict__ conn, float4* __restrict__ pt) {
    int gid = blockIdx.x * blockDim.x + threadIdx.x; // over 256*16*64
    int j = gid & 63;
    int r = (gid >> 6) & 15;
    int k = gid >> 10;
    const float* M = conn + ((size_t)k << 12);
    float4 o;
    o.x = M[(4 * r + 0) * 64 + j];
    o.y = M[(4 * r + 1) * 64 + j];
    o.z = M[(4 * r + 2) * 64 + j];
    o.w = M[(4 * r + 3) * 64 + j];
    pt[gid] = o;
}

__device__ __forceinline__ float bcast(float x, int l) {
    return __int_as_float(__builtin_amdgcn_readlane(__float_as_int(x), l));
}

__device__ __forceinline__ float stepmul(float acc, const float4 buf[16]) {
    float p0 = 0.f, p1 = 0.f, p2 = 0.f, p3 = 0.f;
    #pragma unroll
    for (int r = 0; r < 16; r += 4) {
        float4 m0 = buf[r], m1 = buf[r + 1], m2 = buf[r + 2], m3 = buf[r + 3];
        p0 = fmaf(bcast(acc, 4*r + 0),  m0.x, p0);
        p0 = fmaf(bcast(acc, 4*r + 1),  m0.y, p0);
        p0 = fmaf(bcast(acc, 4*r + 2),  m0.z, p0);
        p0 = fmaf(bcast(acc, 4*r + 3),  m0.w, p0);
        p1 = fmaf(bcast(acc, 4*r + 4),  m1.x, p1);
        p1 = fmaf(bcast(acc, 4*r + 5),  m1.y, p1);
        p1 = fmaf(bcast(acc, 4*r + 6),  m1.z, p1);
        p1 = fmaf(bcast(acc, 4*r + 7),  m1.w, p1);
        p2 = fmaf(bcast(acc, 4*r + 8),  m2.x, p2);
        p2 = fmaf(bcast(acc, 4*r + 9),  m2.y, p2);
        p2 = fmaf(bcast(acc, 4*r + 10), m2.z, p2);
        p2 = fmaf(bcast(acc, 4*r + 11), m2.w, p2);
        p3 = fmaf(bcast(acc, 4*r + 12), m3.x, p3);
        p3 = fmaf(bcast(acc, 4*r + 13), m3.y, p3);
        p3 = fmaf(bcast(acc, 4*r + 14), m3.z, p3);
        p3 = fmaf(bcast(acc, 4*r + 15), m3.w, p3);
    }
    return (p0 + p1) + (p2 + p3);
}

__global__ void __launch_bounds__(256) k_chain(
    const float* __restrict__ fiber, const uint8_t* __restrict__ idx,
    const float4* __restrict__ pt, float* __restrict__ out)
{
    __shared__ uint64_t sidx64[4][64]; // 512 idx bytes per wave's element
    int wid  = threadIdx.x >> 6;
    int lane = threadIdx.x & 63;
    int b = blockIdx.x * 4 + wid;

    // stage this element's 512 index bytes into LDS (one b64 per lane)
    sidx64[wid][lane] = ((const uint64_t*)(idx + (size_t)b * PLEN))[lane];
    __syncthreads();
    const uint8_t* si = (const uint8_t*)sidx64[wid];

    float acc = fiber[b * FD + lane]; // lane j holds v[j]

    float4 bufA[16], bufB[16];

    // prologue: load matrix for step 0
    int k0 = __builtin_amdgcn_readfirstlane((int)si[0]);
    {
        const float4* M = pt + ((size_t)k0 << 10);
        #pragma unroll
        for (int r = 0; r < 16; ++r) bufA[r] = M[r * 64 + lane];
    }
    int kn = (int)si[1];

    for (int i = 0; i < 255; ++i) {
        // issue loads for step 2i+1
        int kb = __builtin_amdgcn_readfirstlane(kn);
        {
            const float4* M = pt + ((size_t)kb << 10);
            #pragma unroll
            for (int r = 0; r < 16; ++r) bufB[r] = M[r * 64 + lane];
        }
        int kn2 = (int)si[2 * i + 2];
        // compute step 2i
        acc = stepmul(acc, bufA);
        // issue loads for step 2i+2
        int ka = __builtin_amdgcn_readfirstlane(kn2);
        {
            const float4* M = pt + ((size_t)ka << 10);
            #pragma unroll
            for (int r = 0; r < 16; ++r) bufA[r] = M[r * 64 + lane];
        }
        kn = (int)si[2 * i + 3]; // i=254 -> si[511] pad byte (never used as a step)
        // compute step 2i+1
        acc = stepmul(acc, bufB);
    }
    // final step 510
    acc = stepmul(acc, bufA);

    out[b * FD + lane] = acc;
}

extern "C" void kernel_launch(void* const* d_in, const int* in_sizes, int n_in,
                              void* d_out, int out_size, void* d_ws, size_t ws_size,
                              hipStream_t stream) {
    const float* fiber = (const float*)d_in[0];
    const float* bp    = (const float*)d_in[1];
    const float* conn  = (const float*)d_in[2];
    float* out = (float*)d_out;

    unsigned int* cm = (unsigned int*)d_ws;
    uint8_t* idx = (uint8_t*)d_ws + 2048;
    float4* pt = (float4*)((uint8_t*)d_ws + 2048 + (size_t)BATCH * PLEN);

    hipLaunchKernelGGL(k_init_colmax, dim3(1), dim3(512), 0, stream, cm);
    hipLaunchKernelGGL(k_colmax, dim3(8, 16), dim3(256), 0, stream, bp, cm);
    hipLaunchKernelGGL(k_idx, dim3((BATCH * PLEN) / 256), dim3(256), 0, stream, bp, cm, idx);
    hipLaunchKernelGGL(k_transpose, dim3(1024), dim3(256), 0, stream, conn, pt);
    hipLaunchKernelGGL(k_chain, dim3(BATCH / 4), dim3(256), 0, stream, fiber, idx, pt, out);
}

// Round 2
// 553.020 us; speedup vs baseline: 1.8749x; 1.8749x over previous
//
#include <hip/hip_runtime.h>
#include <stdint.h>

#define BATCH 4096
#define PLEN  512
#define NSTEP 511
#define FD    64

// ws layout:
//   [0, 2048)                 : colmax bits (512 x u32), init 1.0f, atomicMax'ed
//   [2048, 2048+BATCH*PLEN)   : idx bytes (u8 per (b,t)), t=511 slot written as 0
//   [then, +2MB)              : PH: residual R = conn - I, packed f16.
//                               PH[(k*8+m)*64 + j] = uint4 of f16 rows 8m..8m+7, col j
// total: ~4.2 MB

__global__ void k_init_colmax(unsigned int* cm) {
    int t = threadIdx.x;
    if (t < PLEN) cm[t] = 0x3f800000u; // bits of 1.0f
}

__global__ void k_colmax(const float* __restrict__ bp, unsigned int* __restrict__ cm) {
    __shared__ float red[256];
    int tx = threadIdx.x & 63;
    int ty = threadIdx.x >> 6;
    int t  = blockIdx.x * 64 + tx;            // 0..511
    int b0 = blockIdx.y * 256 + ty * 64;      // 64-row group per wave
    const float* p = bp + (size_t)b0 * PLEN + t;
    float m = 0.0f;
    #pragma unroll 4
    for (int r = 0; r < 64; ++r) {
        m = fmaxf(m, p[(size_t)r * PLEN]);
    }
    red[threadIdx.x] = m;
    __syncthreads();
    if (ty == 0) {
        m = fmaxf(fmaxf(red[tx], red[64 + tx]), fmaxf(red[128 + tx], red[192 + tx]));
        atomicMax((int*)&cm[t], __float_as_int(m)); // values >= 0 -> int-bits monotone
    }
}

__global__ void k_idx(const float* __restrict__ bp, const unsigned int* __restrict__ cm,
                      uint8_t* __restrict__ idx) {
    int gid = blockIdx.x * blockDim.x + threadIdx.x; // over BATCH*PLEN
    int t = gid & (PLEN - 1);
    uint8_t k = 0;
    if (t < NSTEP) {
        float mx = __uint_as_float(cm[t]);    // = max(batch max, 1.0)
        float v  = bp[gid];
        float q  = (v * 256.0f) / mx;         // exact reference order: (bp*base_dim)/mx
        int ik = (int)q;                      // trunc toward zero, matches astype(int32)
        ik = ik < 0 ? 0 : (ik > 255 ? 255 : ik);
        k = (uint8_t)ik;
    }
    idx[gid] = k;
}

__device__ __forceinline__ unsigned short f2h(float x) {
    _Float16 h = (_Float16)x;                 // RNE conversion
    return __builtin_bit_cast(unsigned short, h);
}

__global__ void k_pack(const float* __restrict__ conn, uint4* __restrict__ ph) {
    int gid = blockIdx.x * blockDim.x + threadIdx.x; // over 256*8*64 = 131072
    int j = gid & 63;
    int m = (gid >> 6) & 7;
    int k = gid >> 9;
    const float* M = conn + ((size_t)k << 12);
    unsigned int w[4];
    #pragma unroll
    for (int d = 0; d < 4; ++d) {
        int i0 = 8 * m + 2 * d, i1 = i0 + 1;
        float x0 = M[i0 * 64 + j] - (i0 == j ? 1.0f : 0.0f); // residual R = M - I
        float x1 = M[i1 * 64 + j] - (i1 == j ? 1.0f : 0.0f);
        w[d] = (unsigned)f2h(x0) | ((unsigned)f2h(x1) << 16);
    }
    ph[gid] = make_uint4(w[0], w[1], w[2], w[3]);
}

// v_fma_mix_f32: P += BC(f32) * f16half(PK)
#define MIXLO(P, BC, PK) \
    asm("v_fma_mix_f32 %0, %1, %2, %0 op_sel_hi:[0,1,0]" : "+v"(P) : "v"(BC), "v"(PK))
#define MIXHI(P, BC, PK) \
    asm("v_fma_mix_f32 %0, %1, %2, %0 op_sel:[0,1,0] op_sel_hi:[0,1,0]" : "+v"(P) : "v"(BC), "v"(PK))

__device__ __forceinline__ float step16(float acc, const uint4 buf[8], float* sa, int lane) {
    sa[lane] = acc;                                   // ds_write_b32 (stride-1, conflict-free)
    asm volatile("s_waitcnt lgkmcnt(0)" ::: "memory"); // cross-lane visibility within the wave
    float p0 = acc, p1 = 0.f, p2 = 0.f, p3 = 0.f;     // p0 carries the identity term
    const float4* sv = (const float4*)sa;
    #pragma unroll
    for (int q = 0; q < 8; ++q) {
        uint4 B = buf[q];                 // f16 rows 8q..8q+7 of column `lane`
        float4 b0 = sv[2 * q];            // broadcast v[8q..8q+3] (uniform-address b128)
        float4 b1 = sv[2 * q + 1];        // broadcast v[8q+4..8q+7]
        MIXLO(p0, b0.x, B.x); MIXHI(p1, b0.y, B.x);
        MIXLO(p2, b0.z, B.y); MIXHI(p3, b0.w, B.y);
        MIXLO(p0, b1.x, B.z); MIXHI(p1, b1.y, B.z);
        MIXLO(p2, b1.z, B.w); MIXHI(p3, b1.w, B.w);
    }
    return (p0 + p1) + (p2 + p3);
}

__global__ void __launch_bounds__(256) k_chain(
    const float* __restrict__ fiber, const uint8_t* __restrict__ idx,
    const uint4* __restrict__ ph, float* __restrict__ out)
{
    __shared__ uint64_t sidx64[4][64];   // 512 idx bytes per wave's element
    __shared__ float4 sacc4[4][16];      // per-wave state broadcast buffer (16B aligned)
    int wid  = threadIdx.x >> 6;
    int lane = threadIdx.x & 63;
    int b = blockIdx.x * 4 + wid;

    sidx64[wid][lane] = ((const uint64_t*)(idx + (size_t)b * PLEN))[lane];
    __syncthreads();
    const uint8_t* si = (const uint8_t*)sidx64[wid];
    float* sa = (float*)&sacc4[wid][0];

    float acc = fiber[b * FD + lane];    // lane j holds v[j]

    uint4 bufA[8], bufB[8];

    // prologue: load residual for step 0
    int k0 = __builtin_amdgcn_readfirstlane((int)si[0]);
    {
        const uint4* M = ph + ((size_t)k0 << 9);
        #pragma unroll
        for (int m = 0; m < 8; ++m) bufA[m] = M[m * 64 + lane];
    }
    int kn = (int)si[1];

    for (int i = 0; i < 255; ++i) {
        // issue loads for step 2i+1
        int kb = __builtin_amdgcn_readfirstlane(kn);
        {
            const uint4* M = ph + ((size_t)kb << 9);
            #pragma unroll
            for (int m = 0; m < 8; ++m) bufB[m] = M[m * 64 + lane];
        }
        int kn2 = (int)si[2 * i + 2];
        acc = step16(acc, bufA, sa, lane);      // compute step 2i
        // issue loads for step 2i+2
        int ka = __builtin_amdgcn_readfirstlane(kn2);
        {
            const uint4* M = ph + ((size_t)ka << 9);
            #pragma unroll
            for (int m = 0; m < 8; ++m) bufA[m] = M[m * 64 + lane];
        }
        kn = (int)si[2 * i + 3];                // i=254 -> si[511] pad byte (unused)
        acc = step16(acc, bufB, sa, lane);      // compute step 2i+1
    }
    acc = step16(acc, bufA, sa, lane);          // final step 510

    out[b * FD + lane] = acc;
}

extern "C" void kernel_launch(void* const* d_in, const int* in_sizes, int n_in,
                              void* d_out, int out_size, void* d_ws, size_t ws_size,
                              hipStream_t stream) {
    const float* fiber = (const float*)d_in[0];
    const float* bp    = (const float*)d_in[1];
    const float* conn  = (const float*)d_in[2];
    float* out = (float*)d_out;

    unsigned int* cm = (unsigned int*)d_ws;
    uint8_t* idx = (uint8_t*)d_ws + 2048;
    uint4* ph = (uint4*)((uint8_t*)d_ws + 2048 + (size_t)BATCH * PLEN);

    hipLaunchKernelGGL(k_init_colmax, dim3(1), dim3(512), 0, stream, cm);
    hipLaunchKernelGGL(k_colmax, dim3(8, 16), dim3(256), 0, stream, bp, cm);
    hipLaunchKernelGGL(k_idx, dim3((BATCH * PLEN) / 256), dim3(256), 0, stream, bp, cm, idx);
    hipLaunchKernelGGL(k_pack, dim3(512), dim3(256), 0, stream, conn, ph);
    hipLaunchKernelGGL(k_chain, dim3(BATCH / 4), dim3(256), 0, stream, fiber, idx, ph, out);
}